// Round 12
// baseline (156.885 us; speedup 1.0000x reference)
//
#include <hip/hip_runtime.h>
#include <hip/hip_bf16.h>

// GATConv, N=8192, F_in=F_out=128, dense 0/1 adjacency (int32).
// Rank-1 logits: e_ij = LeakyReLU(es_i + ed_j), es = X@(W@a_src), ed = X@(W@a_dst).
// exp safe in f32 -> additive softmax partials, no max-shift.
//
// R12 architecture (decoupled, all-proven pieces):
//   kA: A (256 MB, mandatory) -> 8 MB bitmask + self-loop, pure streamer (~5 TB/s).
//   k1: W@a vecs, es/ed, H in MFMA-B-frag-major layout VB (validated R11).
//   k2: bits-driven masked GEMM. 512 blocks x 8 waves; wave = (row-group,
//       col-half) -> fully disjoint tiles: P in-reg (exp direct; self-loop
//       pre-baked), VB 2-step-deep register prefetch, NO LDS / barriers /
//       atomics. den via shfl; plain disjoint stores of 4 j-quarter partials.
//   k3: sum partials, divide, ELU.

typedef __bf16 bf16_t;
typedef bf16_t bf16x8 __attribute__((ext_vector_type(8)));
typedef float  f32x4  __attribute__((ext_vector_type(4)));
typedef int    i32x4  __attribute__((ext_vector_type(4)));

#define NN 8192
#define DD 128
#define JSPLIT 4

// ---- kA: pack adjacency to bitmask, self-loop diagonal OR'd in ----
__global__ __launch_bounds__(256) void kA_pack(const int* __restrict__ A,
                                               unsigned* __restrict__ bits) {
  const int w = blockIdx.x * 256 + threadIdx.x;  // word id, 0..2M-1
  const i32x4* p = (const i32x4*)(A + (size_t)w * 32);
  i32x4 v[8];
  #pragma unroll
  for (int q = 0; q < 8; ++q) v[q] = p[q];
  unsigned m = 0;
  #pragma unroll
  for (int q = 0; q < 8; ++q) {
    #pragma unroll
    for (int e = 0; e < 4; ++e) m |= ((unsigned)v[q][e]) << (q * 4 + e);  // A is 0/1
  }
  const int row = w >> 8;         // w / 256
  const int c0 = (w & 255) << 5;  // first col of this word
  if (row >= c0 && row < c0 + 32) m |= 1u << (row - c0);  // self-loop
  bits[w] = m;
}

// ---- K1: fused wv = W@a_{src,dst}; es/ed; VB = frag-major bf16(X@W) ----
__global__ __launch_bounds__(512) void k1_fused(const float* __restrict__ X,
                                                const float* __restrict__ W,
                                                const float* __restrict__ a_src,
                                                const float* __restrict__ a_dst,
                                                float* __restrict__ es,
                                                float* __restrict__ edv,
                                                bf16_t* __restrict__ VB) {
  __shared__ float Wl[DD * DD];
  __shared__ bf16_t Tl[DD][40];
  const int t = threadIdx.x;
  const int rb = blockIdx.x << 5;

  if (t < 256) {
    const int k = t & 127;
    const float* av = (t < 128) ? a_src : a_dst;
    const f32x4* wrow = (const f32x4*)(W + k * DD);
    float s = 0.f;
    #pragma unroll
    for (int c4 = 0; c4 < 32; ++c4) {
      const f32x4 wv = wrow[c4];
      const f32x4 avv = *(const f32x4*)(av + c4 * 4);
      s += wv[0] * avv[0] + wv[1] * avv[1] + wv[2] * avv[2] + wv[3] * avv[3];
    }
    Wl[t] = s;
  }
  if (t < 64) Wl[256 + t] = 0.f;
  __syncthreads();

  {
    const int r = t >> 4, part = t & 15;
    const f32x4* xrow = (const f32x4*)(X + (size_t)(rb + r) * DD + part * 8);
    float s = 0.f, d = 0.f;
    #pragma unroll
    for (int q = 0; q < 2; ++q) {
      const f32x4 xv = xrow[q];
      const f32x4 sv = *(const f32x4*)(Wl + part * 8 + q * 4);
      const f32x4 dv = *(const f32x4*)(Wl + 128 + part * 8 + q * 4);
      s += xv[0] * sv[0] + xv[1] * sv[1] + xv[2] * sv[2] + xv[3] * sv[3];
      d += xv[0] * dv[0] + xv[1] * dv[1] + xv[2] * dv[2] + xv[3] * dv[3];
    }
    atomicAdd(&Wl[256 + r], s);
    atomicAdd(&Wl[288 + r], d);
  }
  __syncthreads();
  if (t < 32) {
    es[rb + t] = Wl[256 + t];
  } else if (t < 64) {
    edv[rb + t - 32] = Wl[288 + t - 32];
  }
  __syncthreads();

  for (int idx = t; idx < DD * DD; idx += 512) Wl[idx] = W[idx];
  __syncthreads();

  const int c = t & 127;
  const int r0 = t >> 7;
  for (int rr = 0; rr < 8; ++rr) {
    const int r = (rr << 2) + r0;
    const f32x4* xrow = (const f32x4*)(X + (size_t)(rb + r) * DD);
    float acc = 0.f;
    #pragma unroll
    for (int k4 = 0; k4 < 32; ++k4) {
      const f32x4 xv = xrow[k4];
      acc += xv[0] * Wl[(k4 * 4 + 0) * DD + c] + xv[1] * Wl[(k4 * 4 + 1) * DD + c] +
             xv[2] * Wl[(k4 * 4 + 2) * DD + c] + xv[3] * Wl[(k4 * 4 + 3) * DD + c];
    }
    Tl[c][r] = (bf16_t)acc;
  }
  __syncthreads();

  // VB[((jb*8 + cb)*64 + lane)*8 + e] = H[jb*32 + (lane>>4)*8 + e][cb*16 + (lane&15)]
  {
    const int cb = t >> 6;
    const int lane = t & 63;
    const int col = (cb << 4) + (lane & 15);
    const int rloc = (lane >> 4) << 3;
    const bf16x8 u = *(const bf16x8*)&Tl[col][rloc];
    *(bf16x8*)(VB + ((((size_t)(rb >> 5) << 3) + cb) * 64 + lane) * 8) = u;
  }
}

// ---- K2: bits-driven masked GEMM. 512 blocks x 512 thr (8 waves). ----
// Block = 64 rows x j-quarter (2048 j, 64 steps of 32). Wave (rg, ch):
// rows rb+rg*16+l16, cols ch*64+cf*16+l16. Everything disjoint: no LDS, no
// barriers, no atomics. VB/ed/bits 2-step-deep register prefetch.
__global__ __launch_bounds__(512, 4) void k2_gat(const unsigned* __restrict__ bits,
                                                 const float* __restrict__ es,
                                                 const float* __restrict__ edv,
                                                 const bf16_t* __restrict__ VB,
                                                 float* __restrict__ num,
                                                 float* __restrict__ denP) {
  const int t = threadIdx.x;
  const int lane = t & 63, wave = t >> 6;
  const int l16 = lane & 15, lk = lane >> 4;
  const int rg = wave >> 1, ch = wave & 1;
  const int rb = (blockIdx.x >> 2) << 6;  // 64 rows
  const int jq = blockIdx.x & 3;
  const int jq0 = jq << 11;

  const int r0 = rb + (rg << 4) + l16;
  const float es0 = es[r0];

  const unsigned* pB = bits + (size_t)r0 * 256 + (jq << 6);  // word per step
  const float* ped = edv + jq0 + (lk << 3);
  const bf16_t* pV = VB + ((((size_t)(jq << 6)) * 8 + (ch << 2)) * 64 + lane) * 8;
  // step stride 4096 elems; cf stride 512 elems

  f32x4 acc[4];
  #pragma unroll
  for (int cf = 0; cf < 4; ++cf) acc[cf] = f32x4{0.f, 0.f, 0.f, 0.f};
  float dsum = 0.f;

  // phase registers (2-deep pipeline), all statically named
  unsigned bw0, bw1;
  f32x4 eA0, eB0, eA1, eB1;
  bf16x8 v00, v01, v02, v03, v10, v11, v12, v13;

  // prologue: steps 0,1
  bw0 = pB[0];
  bw1 = pB[1];
  eA0 = *(const f32x4*)ped;
  eB0 = *(const f32x4*)(ped + 4);
  eA1 = *(const f32x4*)(ped + 32);
  eB1 = *(const f32x4*)(ped + 36);
  v00 = *(const bf16x8*)(pV);
  v01 = *(const bf16x8*)(pV + 512);
  v02 = *(const bf16x8*)(pV + 1024);
  v03 = *(const bf16x8*)(pV + 1536);
  v10 = *(const bf16x8*)(pV + 4096);
  v11 = *(const bf16x8*)(pV + 4096 + 512);
  v12 = *(const bf16x8*)(pV + 4096 + 1024);
  v13 = *(const bf16x8*)(pV + 4096 + 1536);

  auto step = [&](int s, unsigned& bw, f32x4& eA, f32x4& eB, bf16x8& w0, bf16x8& w1,
                  bf16x8& w2, bf16x8& w3) {
    // P in-reg (self-loop already in bits; no compare)
    const unsigned mb = bw >> (lk << 3);
    bf16x8 pa;
    float ps = 0.f;
    #pragma unroll
    for (int e = 0; e < 8; ++e) {
      const float edq = (e < 4) ? eA[e] : eB[e - 4];
      float x = es0 + edq;
      x = fmaxf(x, 0.2f * x);
      const float p = ((mb >> e) & 1u) ? __expf(x) : 0.f;
      ps += p;
      pa[e] = (bf16_t)p;
    }
    dsum += ps;
    // MFMA on this step's fragments (loaded 2 steps ago)
    acc[0] = __builtin_amdgcn_mfma_f32_16x16x32_bf16(pa, w0, acc[0], 0, 0, 0);
    acc[1] = __builtin_amdgcn_mfma_f32_16x16x32_bf16(pa, w1, acc[1], 0, 0, 0);
    acc[2] = __builtin_amdgcn_mfma_f32_16x16x32_bf16(pa, w2, acc[2], 0, 0, 0);
    acc[3] = __builtin_amdgcn_mfma_f32_16x16x32_bf16(pa, w3, acc[3], 0, 0, 0);
    // prefetch step s+2 into the just-consumed phase registers
    if (s + 2 < 64) {
      const int o = (s + 2) << 5;  // j offset
      bw = pB[s + 2];
      eA = *(const f32x4*)(ped + o);
      eB = *(const f32x4*)(ped + o + 4);
      const bf16_t* pv = pV + (size_t)(s + 2) * 4096;
      w0 = *(const bf16x8*)(pv);
      w1 = *(const bf16x8*)(pv + 512);
      w2 = *(const bf16x8*)(pv + 1024);
      w3 = *(const bf16x8*)(pv + 1536);
    }
  };

  #pragma unroll 1
  for (int g = 0; g < 32; ++g) {
    step(2 * g, bw0, eA0, eB0, v00, v01, v02, v03);
    step(2 * g + 1, bw1, eA1, eB1, v10, v11, v12, v13);
  }

  // den: reduce over lk groups (rows identical for l16-equal lanes); ch=0 only
  dsum += __shfl_xor(dsum, 16, 64);
  dsum += __shfl_xor(dsum, 32, 64);
  if (ch == 0 && lane < 16) denP[(size_t)jq * NN + r0] = dsum;

  // num: disjoint plain stores (C/D: row=(lane>>4)*4+reg, col=lane&15)
  float* nq = num + (size_t)jq * (NN * DD);
  #pragma unroll
  for (int cf = 0; cf < 4; ++cf) {
    const int col = (ch << 6) + (cf << 4) + l16;
    #pragma unroll
    for (int r = 0; r < 4; ++r) {
      nq[(size_t)(rb + (rg << 4) + (lk << 2) + r) * DD + col] = acc[cf][r];
    }
  }
}

// ---- K3: out = elu( (sum_q num_q) / (sum_q den_q) ) ----
__global__ __launch_bounds__(256) void k3_fin(const float* __restrict__ num,
                                              const float* __restrict__ denP,
                                              float* __restrict__ out) {
  const int g = blockIdx.x * 256 + threadIdx.x;
  const size_t b = (size_t)g * 8;
  const int row = (int)(b >> 7);
  float den = 0.f;
  #pragma unroll
  for (int q = 0; q < JSPLIT; ++q) den += denP[(size_t)q * NN + row];
  const float rd = 1.f / den;
  f32x4 s0 = {0.f, 0.f, 0.f, 0.f}, s1 = {0.f, 0.f, 0.f, 0.f};
  #pragma unroll
  for (int q = 0; q < JSPLIT; ++q) {
    const float* nb = num + (size_t)q * (NN * DD);
    s0 += *(const f32x4*)(nb + b);
    s1 += *(const f32x4*)(nb + b + 4);
  }
  #pragma unroll
  for (int e = 0; e < 4; ++e) {
    float v = s0[e] * rd;
    s0[e] = v > 0.f ? v : (__expf(v) - 1.f);
    v = s1[e] * rd;
    s1[e] = v > 0.f ? v : (__expf(v) - 1.f);
  }
  *(f32x4*)(out + b) = s0;
  *(f32x4*)(out + b + 4) = s1;
}

extern "C" void kernel_launch(void* const* d_in, const int* in_sizes, int n_in,
                              void* d_out, int out_size, void* d_ws, size_t ws_size,
                              hipStream_t stream) {
  const float* X = (const float*)d_in[0];
  const int* A = (const int*)d_in[1];
  const float* W = (const float*)d_in[2];
  const float* a_src = (const float*)d_in[3];
  const float* a_dst = (const float*)d_in[4];
  float* out = (float*)d_out;

  char* w = (char*)d_ws;
  unsigned* bitsv = (unsigned*)(w + 0);  // 8 MB
  bf16_t* VB = (bf16_t*)(w + 8388608);   // 2 MB frag-major H
  float* es = (float*)(w + 10485760);    // 32 KB
  float* edv = (float*)(w + 10518528);   // 32 KB
  float* denP = (float*)(w + 10551296);  // 4 x 32 KB
  float* num = (float*)(w + 10682368);   // 4 x 4 MB (total ~27 MB)

  hipLaunchKernelGGL(kA_pack, dim3(NN * NN / 32 / 256), dim3(256), 0, stream, A, bitsv);
  hipLaunchKernelGGL(k1_fused, dim3(256), dim3(512), 0, stream, X, W, a_src, a_dst, es,
                     edv, VB);
  hipLaunchKernelGGL(k2_gat, dim3(512), dim3(512), 0, stream, bitsv, es, edv, VB, num,
                     denP);
  hipLaunchKernelGGL(k3_fin, dim3(512), dim3(256), 0, stream, num, denP, out);
}